// Round 2
// baseline (87.194 us; speedup 1.0000x reference)
//
#include <hip/hip_runtime.h>
#include <math.h>

// Tropical (max-plus) matmul: y[b,o] = max_i (x[b,i] + W[o,i])
// x: [512,1024] f32, W: [1024,1024] f32 (K-innermost), y: [512,1024] f32.
//
// VALU-bound (no MFMA for max-plus; no fp32 MFMA on CDNA4). Floor ~10 us with
// v_max3. Split-K (KS=16) -> partial-max slices in ws, then reduce. Exact.
//
// R1 finding: dur_us includes the harness's 268 MB ws re-poison fill (~41 us,
// unavoidable, happens whether or not we use ws) -> using ws is free.

#define MDIM 512
#define NDIM 1024
#define KDIM 1024

#define BM 128
#define BN 64
#define BK 32
#define TM 8
#define TN 4
#define NTHREADS 256
#define LDA (BM + 4)   // 132: A-write bank = (am + c) % 32, am=t>>1 -> 2-way (free)
#define LDB (BN + 4)   // 68

__global__ __launch_bounds__(NTHREADS, 4)
void tropical_partial(const float* __restrict__ x, const float* __restrict__ W,
                      float* __restrict__ ws, int KC) {
    __shared__ float As[BK][LDA];   // k-major: frag reads contiguous in m (b128)
    __shared__ float Bs[BK][LDB];

    const int tiles_n = NDIM / BN;               // 16
    const int tile = blockIdx.x;                 // 0..63
    const int tm0 = (tile / tiles_n) * BM;
    const int tn0 = (tile % tiles_n) * BN;
    const int k0  = blockIdx.y * KC;

    const int t = threadIdx.x;

    // A staging: m = t>>1 (0..127), k base (t&1)*16, 4x float4 at +{0,4,8,12}
    const int am = t >> 1;
    const int ak = (t & 1) * 16;
    // B staging: n = t>>2 (0..63), k base (t&3)*4, 2x float4 at +{0,16}
    //   write bank = (16*(t&3) + 4j + bn) % 32 -> <=2-way (free)
    const int bn = t >> 2;
    const int bk = (t & 3) * 4;

    const float* xp = x + (size_t)(tm0 + am) * KDIM + k0 + ak;
    const float* wp = W + (size_t)(tn0 + bn) * KDIM + k0 + bk;

    // compute map: 16x16 threads, each 8x4 outputs
    const int ty = t >> 4;     // m = ty*8
    const int tx = t & 15;     // n = tx*4

    float acc[TM][TN];
#pragma unroll
    for (int i = 0; i < TM; ++i)
#pragma unroll
        for (int j = 0; j < TN; ++j) acc[i][j] = -INFINITY;

    float4 al[4], bl[2];
    al[0] = *(const float4*)(xp + 0);
    al[1] = *(const float4*)(xp + 4);
    al[2] = *(const float4*)(xp + 8);
    al[3] = *(const float4*)(xp + 12);
    bl[0] = *(const float4*)(wp + 0);
    bl[1] = *(const float4*)(wp + 16);

    const int rounds = KC / BK;
    for (int r = 0; r < rounds; ++r) {
        __syncthreads();   // previous round's frag reads complete
#pragma unroll
        for (int q = 0; q < 4; ++q) {
            As[ak + q * 4 + 0][am] = al[q].x;
            As[ak + q * 4 + 1][am] = al[q].y;
            As[ak + q * 4 + 2][am] = al[q].z;
            As[ak + q * 4 + 3][am] = al[q].w;
        }
        Bs[bk + 0][bn] = bl[0].x;  Bs[bk + 1][bn] = bl[0].y;
        Bs[bk + 2][bn] = bl[0].z;  Bs[bk + 3][bn] = bl[0].w;
        Bs[bk + 16][bn] = bl[1].x; Bs[bk + 17][bn] = bl[1].y;
        Bs[bk + 18][bn] = bl[1].z; Bs[bk + 19][bn] = bl[1].w;
        __syncthreads();

        if (r + 1 < rounds) {   // prefetch next round under this round's compute
            xp += BK; wp += BK;
            al[0] = *(const float4*)(xp + 0);
            al[1] = *(const float4*)(xp + 4);
            al[2] = *(const float4*)(xp + 8);
            al[3] = *(const float4*)(xp + 12);
            bl[0] = *(const float4*)(wp + 0);
            bl[1] = *(const float4*)(wp + 16);
        }

#pragma unroll
        for (int kk = 0; kk < BK; kk += 2) {
            const float4 a00 = *(const float4*)&As[kk][ty * 8];
            const float4 a01 = *(const float4*)&As[kk][ty * 8 + 4];
            const float4 a10 = *(const float4*)&As[kk + 1][ty * 8];
            const float4 a11 = *(const float4*)&As[kk + 1][ty * 8 + 4];
            const float4 b0v = *(const float4*)&Bs[kk][tx * 4];
            const float4 b1v = *(const float4*)&Bs[kk + 1][tx * 4];
            const float a0[8] = {a00.x, a00.y, a00.z, a00.w, a01.x, a01.y, a01.z, a01.w};
            const float a1[8] = {a10.x, a10.y, a10.z, a10.w, a11.x, a11.y, a11.z, a11.w};
            const float b0[4] = {b0v.x, b0v.y, b0v.z, b0v.w};
            const float b1[4] = {b1v.x, b1v.y, b1v.z, b1v.w};
#pragma unroll
            for (int i = 0; i < TM; ++i)
#pragma unroll
                for (int j = 0; j < TN; ++j)
                    // 2 adds + v_max3 per 2 k-steps: 3 VALU per 2 pairs
                    acc[i][j] = fmaxf(fmaxf(acc[i][j], a0[i] + b0[j]), a1[i] + b1[j]);
        }
    }

    float* o = ws + (size_t)blockIdx.y * MDIM * NDIM;
#pragma unroll
    for (int i = 0; i < TM; ++i) {
        const float4 v = make_float4(acc[i][0], acc[i][1], acc[i][2], acc[i][3]);
        *(float4*)&o[(size_t)(tm0 + ty * TM + i) * NDIM + tn0 + tx * TN] = v;
    }
}

__global__ __launch_bounds__(NTHREADS)
void tropical_reduce(const float* __restrict__ ws, float* __restrict__ out, int KS) {
    const int i = blockIdx.x * NTHREADS + threadIdx.x;   // float4 index
    const int stride = MDIM * NDIM / 4;
    if (i >= stride) return;
    const float4* w4 = (const float4*)ws;
    float4 m = w4[i];
    for (int s = 1; s < KS; ++s) {
        const float4 v = w4[(size_t)s * stride + i];
        m.x = fmaxf(m.x, v.x); m.y = fmaxf(m.y, v.y);
        m.z = fmaxf(m.z, v.z); m.w = fmaxf(m.w, v.w);
    }
    ((float4*)out)[i] = m;
}

extern "C" void kernel_launch(void* const* d_in, const int* in_sizes, int n_in,
                              void* d_out, int out_size, void* d_ws, size_t ws_size,
                              hipStream_t stream) {
    const float* x = (const float*)d_in[0];
    const float* W = (const float*)d_in[1];
    float* out = (float*)d_out;
    float* ws  = (float*)d_ws;

    const size_t slice = (size_t)MDIM * NDIM * sizeof(float);  // 2 MB
    int KS = 16;                                               // 1024 blocks, 4/CU
    while (KS > 1 && (size_t)KS * slice > ws_size) KS >>= 1;

    const int ntiles = (MDIM / BM) * (NDIM / BN);  // 64

    if ((size_t)KS * slice > ws_size) {
        // tiny-workspace fallback: full K straight into out
        tropical_partial<<<dim3(ntiles, 1), NTHREADS, 0, stream>>>(x, W, out, KDIM);
        return;
    }

    const int KC = KDIM / KS;   // 64 at KS=16 (2 rounds of BK=32)
    tropical_partial<<<dim3(ntiles, KS), NTHREADS, 0, stream>>>(x, W, ws, KC);

    const int nvec4 = MDIM * NDIM / 4;
    tropical_reduce<<<(nvec4 + NTHREADS - 1) / NTHREADS, NTHREADS, 0, stream>>>(ws, out, KS);
}